// Round 18
// baseline (37.007 us; speedup 1.0000x reference)
//
#include <hip/hip_runtime.h>
#include <hip/hip_bf16.h>

typedef __attribute__((ext_vector_type(4))) float f32x4;
typedef __attribute__((ext_vector_type(2))) long i64x2;

typedef const __attribute__((address_space(1))) void* gptr_t;
typedef __attribute__((address_space(3))) void* lptr_t;

#define NROW 8192
#define DDIM 256
#define HALF_B 4096
#define NB 64                        // 8192/128 tile bands
#define NTILES (NB * (NB + 1) / 2)   // 2080 upper-triangle tiles

// exp(dot/T) = exp2(dot * log2(e)/T), T = 0.07
#define E2SCALE 20.6099291555566196f
#define INV_T   14.2857142857142858f

__device__ __forceinline__ float fast_exp2(float x) {
  float r;
  asm("v_exp_f32 %0, %1" : "=v"(r) : "v"(x));
  return r;
}

// ---------------- kernel 1: normalize + fp8(e4m3) quant, paired layout -----
// (R10/R14-validated) byte = row*256 + (p>>1)*128 + ((((p&1)<<2)|g)^(row&7))*16
// + e*8 + o: half-K runs are linear for global_load_lds; ds_read conflict-free.
__global__ __launch_bounds__(256) void normalize_kernel(
    const float* __restrict__ z_i, const float* __restrict__ z_j,
    unsigned char* __restrict__ zn, float* __restrict__ lacc,
    unsigned int* __restrict__ counter) {
  const int lane = threadIdx.x & 63;
  const int w = blockIdx.x * 4 + (threadIdx.x >> 6);  // wave id 0..2047
  const int g  = (lane >> 1) & 3;
  const int e  = (lane >> 3) & 1;
  const int ph = (lane >> 4) & 1;
  const int pq = lane >> 5;
  const int o  = (lane & 1) * 4;
  const int cbase = (ph << 2) | g;
  for (int row = w; row < NROW; row += 2048) {
    const float* src = (row < HALF_B) ? (z_i + (size_t)row * DDIM)
                                      : (z_j + (size_t)(row - HALF_B) * DDIM);
    float4 v = *reinterpret_cast<const float4*>(src + lane * 4);
    float ss = v.x * v.x + v.y * v.y + v.z * v.z + v.w * v.w;
#pragma unroll
    for (int m = 32; m; m >>= 1) ss += __shfl_xor(ss, m);
    const float inv = 1.0f / sqrtf(ss);
    int pk = __builtin_amdgcn_cvt_pk_fp8_f32(v.x * inv, v.y * inv, 0, false);
    pk = __builtin_amdgcn_cvt_pk_fp8_f32(v.z * inv, v.w * inv, pk, true);
    const int pos = pq * 128 + ((cbase ^ (row & 7)) << 4) + e * 8 + o;
    *reinterpret_cast<unsigned int*>(zn + (size_t)row * DDIM + pos) =
        (unsigned int)pk;
  }
  if (blockIdx.x == 0 && threadIdx.x == 0) { *lacc = 0.0f; *counter = 0u; }
}

// ---------------- kernel 2: 128x128 Gram tiles, 256 thr, 4 blocks/CU --------
// R17 structure (4-deep block overlap) + two refinements:
//  (a) early lgkm-barrier: after lp1's ds_reads retire (operands in VGPRs),
//      s_barrier releases the buffer and stage(h1) is issued IN THE SHADOW of
//      lp1's 32 MFMAs — shrinks the mid-block restage window.
//  (b) bijective XCD swizzle (2080 = 8*260): blocks with equal bid%8 process
//      260 consecutive tri-order tiles -> same-band A rows share one XCD L2.
__global__ __launch_bounds__(256, 4) void gram_kernel(
    const unsigned char* __restrict__ zn,
    float* __restrict__ P, float* __restrict__ pos) {
  __shared__ char smem[33792];   // A@0 B@16384 | colmat @32768 (1KB)
  float (*colmat)[2] = (float (*)[2])(smem + 32768);

  const int tid = threadIdx.x;
  const int lane = tid & 63;
  const int wid = tid >> 6;          // 0..3
  const int wr = wid >> 1;           // 0..1 (64 rows)
  const int wc = wid & 1;            // 0..1 (64 cols)

  // XCD-bijective tile swizzle: 2080 tiles = 8 XCDs x 260
  int p = (blockIdx.x & 7) * 260 + (blockIdx.x >> 3);
  int by = 0;
  while (p >= NB - by) { p -= NB - by; ++by; }
  const int bx = by + p;
  const int rowBase = by * 128;
  const int colBase = bx * 128;
  const bool isdiag = (bx == by);
  const bool ispos = (bx - by == 32);

  const int rloc = tid >> 3;         // 0..31
  const int c16 = (tid & 7) * 16;
  const int r15 = lane & 15, g = lane >> 4, r7 = lane & 7;
  const int abase = (wr * 64 + r15) * 128;
  const int bbase = (wc * 64 + r15) * 128;

  auto stage = [&](int h) {
#pragma unroll
    for (int i = 0; i < 4; ++i) {
      const int r = i * 32 + rloc;
      const unsigned char* ga =
          zn + (size_t)(rowBase + r) * DDIM + h * 128 + c16;
      __builtin_amdgcn_global_load_lds((gptr_t)ga,
          (lptr_t)(smem + i * 4096 + wid * 1024), 16, 0, 0);
    }
#pragma unroll
    for (int i = 0; i < 4; ++i) {
      const int r = i * 32 + rloc;
      const unsigned char* gb =
          zn + (size_t)(colBase + r) * DDIM + h * 128 + c16;
      __builtin_amdgcn_global_load_lds((gptr_t)gb,
          (lptr_t)(smem + 16384 + i * 4096 + wid * 1024), 16, 0, 0);
    }
  };

  f32x4 acc[4][4] = {};

  auto mfma16 = [&](const long* a, const long* b) {
#pragma unroll
    for (int m = 0; m < 4; ++m)
#pragma unroll
      for (int n = 0; n < 4; ++n)
        acc[m][n] = __builtin_amdgcn_mfma_f32_16x16x32_fp8_fp8(
            a[m], b[n], acc[m][n], 0, 0, 0);
  };

  stage(0);
  asm volatile("s_waitcnt vmcnt(0)" ::: "memory");
  __builtin_amdgcn_s_barrier();
  __builtin_amdgcn_sched_barrier(0);

#pragma unroll
  for (int h = 0; h < 2; ++h) {
    const char* Ab = reinterpret_cast<const char*>(smem);
    const char* Bb = reinterpret_cast<const char*>(smem) + 16384;
    // ---- lp0: reads + MFMAs
    {
      const int off = ((g ^ r7) << 4);
      i64x2 A0 = *reinterpret_cast<const i64x2*>(Ab + abase + off);
      i64x2 A1 = *reinterpret_cast<const i64x2*>(Ab + abase + 2048 + off);
      i64x2 A2 = *reinterpret_cast<const i64x2*>(Ab + abase + 4096 + off);
      i64x2 A3 = *reinterpret_cast<const i64x2*>(Ab + abase + 6144 + off);
      i64x2 B0 = *reinterpret_cast<const i64x2*>(Bb + bbase + off);
      i64x2 B1 = *reinterpret_cast<const i64x2*>(Bb + bbase + 2048 + off);
      i64x2 B2 = *reinterpret_cast<const i64x2*>(Bb + bbase + 4096 + off);
      i64x2 B3 = *reinterpret_cast<const i64x2*>(Bb + bbase + 6144 + off);
#pragma unroll
      for (int e = 0; e < 2; ++e) {
        const long a[4] = {A0[e], A1[e], A2[e], A3[e]};
        const long b[4] = {B0[e], B1[e], B2[e], B3[e]};
        mfma16(a, b);
      }
    }
    // ---- lp1: reads, then EARLY barrier (buffer free once reads retire),
    //      stage(h1) in the shadow of lp1's MFMAs
    {
      const int off = (((4 | g) ^ r7) << 4);
      i64x2 A0 = *reinterpret_cast<const i64x2*>(Ab + abase + off);
      i64x2 A1 = *reinterpret_cast<const i64x2*>(Ab + abase + 2048 + off);
      i64x2 A2 = *reinterpret_cast<const i64x2*>(Ab + abase + 4096 + off);
      i64x2 A3 = *reinterpret_cast<const i64x2*>(Ab + abase + 6144 + off);
      i64x2 B0 = *reinterpret_cast<const i64x2*>(Bb + bbase + off);
      i64x2 B1 = *reinterpret_cast<const i64x2*>(Bb + bbase + 2048 + off);
      i64x2 B2 = *reinterpret_cast<const i64x2*>(Bb + bbase + 4096 + off);
      i64x2 B3 = *reinterpret_cast<const i64x2*>(Bb + bbase + 6144 + off);
      asm volatile("s_waitcnt lgkmcnt(0)" ::: "memory");
      __builtin_amdgcn_sched_barrier(0);
      __builtin_amdgcn_s_barrier();          // all waves' half-h reads done
      if (h == 0) {
        stage(1);                            // overwrite freed buffer
        __builtin_amdgcn_sched_barrier(0);   // pin issue before MFMAs
      }
#pragma unroll
      for (int e = 0; e < 2; ++e) {
        const long a[4] = {A0[e], A1[e], A2[e], A3[e]};
        const long b[4] = {B0[e], B1[e], B2[e], B3[e]};
        mfma16(a, b);
      }
      if (h == 0) {
        asm volatile("s_waitcnt vmcnt(0)" ::: "memory");
        __builtin_amdgcn_s_barrier();        // h1 data visible to all waves
        __builtin_amdgcn_sched_barrier(0);
      }
    }
  }
  // (no trailing barrier: last early barrier already released the buffer)

  // ---- epilogue ph1: exp + scatter row-partials into swizzled rowmat
  // rowmat: 128 rows x 32 slots, byte = lrow*256 + (((slot>>2)^(lrow&15))<<4)
  //         + ((slot&3)<<2)   (R15/R17-validated algebra)
  char* rowm = smem;
  float colpart[4] = {0.0f, 0.0f, 0.0f, 0.0f};
  const int slot = wc * 16 + r15;    // 0..31
#pragma unroll
  for (int m = 0; m < 4; ++m) {
#pragma unroll
    for (int v = 0; v < 4; ++v) {
      const int lrow = wr * 64 + m * 16 + (lane >> 4) * 4 + v;
      const int gi = rowBase + lrow;
      float rp = 0.0f;
#pragma unroll
      for (int n = 0; n < 4; ++n) {
        const float d = acc[m][n][v];
        float val = fast_exp2(d * E2SCALE);
        if (isdiag) {
          const int gj = colBase + wc * 64 + n * 16 + r15;
          if (gi == gj) val = 0.0f;           // exclude diagonal
        } else if (ispos) {
          const int gj = colBase + wc * 64 + n * 16 + r15;
          if (gj == gi + HALF_B) {            // positive pair
            const float pv = d * INV_T;
            pos[gi] = pv;
            pos[gj] = pv;
          }
        }
        rp += val;
        colpart[n] += val;
      }
      const int bo = (lrow << 8) + ((((slot >> 2) ^ (lrow & 15)) << 4)) +
                     ((slot & 3) << 2);
      *reinterpret_cast<float*>(rowm + bo) = rp;
    }
  }
#pragma unroll
  for (int n = 0; n < 4; ++n) {
    float c = colpart[n];
    c += __shfl_xor(c, 16);
    c += __shfl_xor(c, 32);
    if (lane < 16) colmat[wc * 64 + n * 16 + lane][wr] = c;
  }
  __syncthreads();

  // ---- epilogue ph2: read-reduce rowmat -> P rows; colmat -> P cols
  {
    const int row = tid >> 1;          // 0..127
    const int half = tid & 1;
    f32x4 s4 = {0.0f, 0.0f, 0.0f, 0.0f};
#pragma unroll
    for (int i = 0; i < 4; ++i) {
      const int c = half * 4 + i;
      s4 += *reinterpret_cast<const f32x4*>(
          rowm + (row << 8) + ((c ^ (row & 15)) << 4));
    }
    float s = (s4[0] + s4[1]) + (s4[2] + s4[3]);
    s += __shfl_xor(s, 1);
    if (half == 0) P[(size_t)bx * NROW + rowBase + row] = s;
  }
  if (tid < 128 && !isdiag) {
    P[(size_t)by * NROW + colBase + tid] = colmat[tid][0] + colmat[tid][1];
  }
}

// -------- kernel 3: row reduction + log + fused finalize (arrival counter) --
__global__ __launch_bounds__(256) void rowreduce_kernel(
    const float* __restrict__ P, const float* __restrict__ pos,
    float* __restrict__ lacc, unsigned int* __restrict__ counter,
    float* __restrict__ out) {
  const int i = blockIdx.x * 256 + threadIdx.x;
  float s = 0.0f;
#pragma unroll 8
  for (int k = 0; k < NB; ++k) s += P[(size_t)k * NROW + i];
  float partial = logf(s) - pos[i];
#pragma unroll
  for (int m = 32; m; m >>= 1) partial += __shfl_xor(partial, m);
  __shared__ float sred[4];
  if ((threadIdx.x & 63) == 0) sred[threadIdx.x >> 6] = partial;
  __syncthreads();
  if (threadIdx.x == 0) {
    atomicAdd(lacc, sred[0] + sred[1] + sred[2] + sred[3]);
    __threadfence();
    const unsigned done = atomicAdd(counter, 1u);
    if (done == (unsigned)(gridDim.x - 1)) {      // last block finalizes
      const float v = atomicAdd(lacc, 0.0f);      // device-coherent read
      out[0] = v * (1.0f / (float)NROW);
    }
  }
}

extern "C" void kernel_launch(void* const* d_in, const int* in_sizes, int n_in,
                              void* d_out, int out_size, void* d_ws, size_t ws_size,
                              hipStream_t stream) {
  const float* z_i = (const float*)d_in[0];
  const float* z_j = (const float*)d_in[1];
  float* out = (float*)d_out;

  char* ws = (char*)d_ws;
  unsigned char* zn = (unsigned char*)ws;                        // 2 MB fp8
  float* pos  = (float*)(ws + 2097152);                          // 32 KB
  float* P    = (float*)(ws + 2097152 + 32768);                  // 2 MB
  float* lacc = (float*)(ws + 2097152 + 32768 + 2097152);        // 4 B
  unsigned int* counter = (unsigned int*)(ws + 2097152 + 32768 + 2097152 + 4);

  normalize_kernel<<<512, 256, 0, stream>>>(z_i, z_j, zn, lacc, counter);
  gram_kernel<<<NTILES, 256, 0, stream>>>(zn, P, pos);
  rowreduce_kernel<<<NROW / 256, 256, 0, stream>>>(P, pos, lacc, counter, out);
}

// Round 19
// 35.984 us; speedup vs baseline: 1.0284x; 1.0284x over previous
//
#include <hip/hip_runtime.h>
#include <hip/hip_bf16.h>

typedef __attribute__((ext_vector_type(4))) float f32x4;
typedef __attribute__((ext_vector_type(2))) long i64x2;

typedef const __attribute__((address_space(1))) void* gptr_t;
typedef __attribute__((address_space(3))) void* lptr_t;

#define NROW 8192
#define DDIM 256
#define HALF_B 4096
#define NB 64                        // 8192/128 tile bands
#define NTILES (NB * (NB + 1) / 2)   // 2080 upper-triangle tiles

// exp(dot/T) = exp2(dot * log2(e)/T), T = 0.07
#define E2SCALE 20.6099291555566196f
#define INV_T   14.2857142857142858f

__device__ __forceinline__ float fast_exp2(float x) {
  float r;
  asm("v_exp_f32 %0, %1" : "=v"(r) : "v"(x));
  return r;
}

// ---------------- kernel 1: normalize + fp8(e4m3) quant, paired layout -----
// (R10/R14-validated) byte = row*256 + (p>>1)*128 + ((((p&1)<<2)|g)^(row&7))*16
// + e*8 + o: half-K runs are linear for global_load_lds; ds_read conflict-free.
__global__ __launch_bounds__(256) void normalize_kernel(
    const float* __restrict__ z_i, const float* __restrict__ z_j,
    unsigned char* __restrict__ zn, float* __restrict__ lacc,
    unsigned int* __restrict__ counter) {
  const int lane = threadIdx.x & 63;
  const int w = blockIdx.x * 4 + (threadIdx.x >> 6);  // wave id 0..2047
  const int g  = (lane >> 1) & 3;
  const int e  = (lane >> 3) & 1;
  const int ph = (lane >> 4) & 1;
  const int pq = lane >> 5;
  const int o  = (lane & 1) * 4;
  const int cbase = (ph << 2) | g;
  for (int row = w; row < NROW; row += 2048) {
    const float* src = (row < HALF_B) ? (z_i + (size_t)row * DDIM)
                                      : (z_j + (size_t)(row - HALF_B) * DDIM);
    float4 v = *reinterpret_cast<const float4*>(src + lane * 4);
    float ss = v.x * v.x + v.y * v.y + v.z * v.z + v.w * v.w;
#pragma unroll
    for (int m = 32; m; m >>= 1) ss += __shfl_xor(ss, m);
    const float inv = 1.0f / sqrtf(ss);
    int pk = __builtin_amdgcn_cvt_pk_fp8_f32(v.x * inv, v.y * inv, 0, false);
    pk = __builtin_amdgcn_cvt_pk_fp8_f32(v.z * inv, v.w * inv, pk, true);
    const int pos = pq * 128 + ((cbase ^ (row & 7)) << 4) + e * 8 + o;
    *reinterpret_cast<unsigned int*>(zn + (size_t)row * DDIM + pos) =
        (unsigned int)pk;
  }
  if (blockIdx.x == 0 && threadIdx.x == 0) { *lacc = 0.0f; *counter = 0u; }
}

// ---------------- kernel 2: 128x128 Gram tiles, 256 thr, 4 blocks/CU --------
// 4 waves (2x2), wave-tile 64x64, acc[4][4]. Half-K staged into ONE 32KB
// buffer (A_h 16K @0, B_h 16K @16K) -> LDS 33KB -> 4 blocks/CU = 4-deep
// block-level latency overlap (R17: the session's strongest lever, -14%).
// ds_read algebra proven conflict-free (R2-R17). Epilogue: swizzled rowmat
// (aliases stage region) + colmat[128][2] @32768.
__global__ __launch_bounds__(256, 4) void gram_kernel(
    const unsigned char* __restrict__ zn,
    float* __restrict__ P, float* __restrict__ pos) {
  __shared__ char smem[33792];   // A@0 B@16384 | colmat @32768 (1KB)
  float (*colmat)[2] = (float (*)[2])(smem + 32768);

  const int tid = threadIdx.x;
  const int lane = tid & 63;
  const int wid = tid >> 6;          // 0..3
  const int wr = wid >> 1;           // 0..1 (64 rows)
  const int wc = wid & 1;            // 0..1 (64 cols)

  int p = blockIdx.x;
  int by = 0;
  while (p >= NB - by) { p -= NB - by; ++by; }
  const int bx = by + p;
  const int rowBase = by * 128;
  const int colBase = bx * 128;
  const bool isdiag = (bx == by);
  const bool ispos = (bx - by == 32);

  const int rloc = tid >> 3;         // 0..31
  const int c16 = (tid & 7) * 16;
  const int r15 = lane & 15, g = lane >> 4, r7 = lane & 7;
  const int abase = (wr * 64 + r15) * 128;
  const int bbase = (wc * 64 + r15) * 128;

  f32x4 acc[4][4] = {};

#pragma unroll
  for (int h = 0; h < 2; ++h) {
    // ---- stage half h: A rows then B rows (linear dest, swizzle in layout)
#pragma unroll
    for (int i = 0; i < 4; ++i) {
      const int r = i * 32 + rloc;
      const unsigned char* ga =
          zn + (size_t)(rowBase + r) * DDIM + h * 128 + c16;
      __builtin_amdgcn_global_load_lds((gptr_t)ga,
          (lptr_t)(smem + i * 4096 + wid * 1024), 16, 0, 0);
    }
#pragma unroll
    for (int i = 0; i < 4; ++i) {
      const int r = i * 32 + rloc;
      const unsigned char* gb =
          zn + (size_t)(colBase + r) * DDIM + h * 128 + c16;
      __builtin_amdgcn_global_load_lds((gptr_t)gb,
          (lptr_t)(smem + 16384 + i * 4096 + wid * 1024), 16, 0, 0);
    }
    asm volatile("s_waitcnt vmcnt(0)" ::: "memory");
    __builtin_amdgcn_s_barrier();
    __builtin_amdgcn_sched_barrier(0);

    const char* Ab = reinterpret_cast<const char*>(smem);
    const char* Bb = reinterpret_cast<const char*>(smem) + 16384;
#pragma unroll
    for (int lp = 0; lp < 2; ++lp) {
      const int off = ((((lp << 2) | g) ^ r7) << 4);
      i64x2 A0 = *reinterpret_cast<const i64x2*>(Ab + abase + off);
      i64x2 A1 = *reinterpret_cast<const i64x2*>(Ab + abase + 2048 + off);
      i64x2 A2 = *reinterpret_cast<const i64x2*>(Ab + abase + 4096 + off);
      i64x2 A3 = *reinterpret_cast<const i64x2*>(Ab + abase + 6144 + off);
      i64x2 B0 = *reinterpret_cast<const i64x2*>(Bb + bbase + off);
      i64x2 B1 = *reinterpret_cast<const i64x2*>(Bb + bbase + 2048 + off);
      i64x2 B2 = *reinterpret_cast<const i64x2*>(Bb + bbase + 4096 + off);
      i64x2 B3 = *reinterpret_cast<const i64x2*>(Bb + bbase + 6144 + off);
#pragma unroll
      for (int e = 0; e < 2; ++e) {
        const long a[4] = {A0[e], A1[e], A2[e], A3[e]};
        const long b[4] = {B0[e], B1[e], B2[e], B3[e]};
#pragma unroll
        for (int m = 0; m < 4; ++m)
#pragma unroll
          for (int n = 0; n < 4; ++n)
            acc[m][n] = __builtin_amdgcn_mfma_f32_16x16x32_fp8_fp8(
                a[m], b[n], acc[m][n], 0, 0, 0);
      }
    }
    __syncthreads();   // all reads of this half done before restage/alias
  }

  // ---- epilogue ph1: exp + scatter row-partials into swizzled rowmat
  // rowmat: 128 rows x 32 partial slots, byte = lrow*256 +
  //   (((slot>>2) ^ (lrow&15))<<4) + ((slot&3)<<2)   (R15-validated algebra)
  char* rowm = smem;
  float colpart[4] = {0.0f, 0.0f, 0.0f, 0.0f};
  const int slot = wc * 16 + r15;    // partial slot 0..31
#pragma unroll
  for (int m = 0; m < 4; ++m) {
#pragma unroll
    for (int v = 0; v < 4; ++v) {
      const int lrow = wr * 64 + m * 16 + (lane >> 4) * 4 + v;
      const int gi = rowBase + lrow;
      float rp = 0.0f;
#pragma unroll
      for (int n = 0; n < 4; ++n) {
        const float d = acc[m][n][v];
        float val = fast_exp2(d * E2SCALE);
        if (isdiag) {
          const int gj = colBase + wc * 64 + n * 16 + r15;
          if (gi == gj) val = 0.0f;           // exclude diagonal
        } else if (ispos) {
          const int gj = colBase + wc * 64 + n * 16 + r15;
          if (gj == gi + HALF_B) {            // positive pair
            const float pv = d * INV_T;
            pos[gi] = pv;
            pos[gj] = pv;
          }
        }
        rp += val;
        colpart[n] += val;
      }
      const int bo = (lrow << 8) + ((((slot >> 2) ^ (lrow & 15)) << 4)) +
                     ((slot & 3) << 2);
      *reinterpret_cast<float*>(rowm + bo) = rp;
    }
  }
  // column partials: reduce over hi groups -> lanes r15<16 hold 64-row sums
#pragma unroll
  for (int n = 0; n < 4; ++n) {
    float c = colpart[n];
    c += __shfl_xor(c, 16);
    c += __shfl_xor(c, 32);
    if (lane < 16) colmat[wc * 64 + n * 16 + lane][wr] = c;
  }
  __syncthreads();

  // ---- epilogue ph2: read-reduce rowmat -> P rows; colmat -> P cols
  {
    const int row = tid >> 1;          // 0..127
    const int half = tid & 1;          // 16 partials each
    f32x4 s4 = {0.0f, 0.0f, 0.0f, 0.0f};
#pragma unroll
    for (int i = 0; i < 4; ++i) {
      const int c = half * 4 + i;      // chunk 0..7
      s4 += *reinterpret_cast<const f32x4*>(
          rowm + (row << 8) + ((c ^ (row & 15)) << 4));
    }
    float s = (s4[0] + s4[1]) + (s4[2] + s4[3]);
    s += __shfl_xor(s, 1);
    if (half == 0) P[(size_t)bx * NROW + rowBase + row] = s;
  }
  if (tid < 128 && !isdiag) {
    P[(size_t)by * NROW + colBase + tid] = colmat[tid][0] + colmat[tid][1];
  }
}

// -------- kernel 3: row reduction + log + fused finalize (arrival counter) --
__global__ __launch_bounds__(256) void rowreduce_kernel(
    const float* __restrict__ P, const float* __restrict__ pos,
    float* __restrict__ lacc, unsigned int* __restrict__ counter,
    float* __restrict__ out) {
  const int i = blockIdx.x * 256 + threadIdx.x;
  float s = 0.0f;
#pragma unroll 8
  for (int k = 0; k < NB; ++k) s += P[(size_t)k * NROW + i];
  float partial = logf(s) - pos[i];
#pragma unroll
  for (int m = 32; m; m >>= 1) partial += __shfl_xor(partial, m);
  __shared__ float sred[4];
  if ((threadIdx.x & 63) == 0) sred[threadIdx.x >> 6] = partial;
  __syncthreads();
  if (threadIdx.x == 0) {
    atomicAdd(lacc, sred[0] + sred[1] + sred[2] + sred[3]);
    __threadfence();
    const unsigned done = atomicAdd(counter, 1u);
    if (done == (unsigned)(gridDim.x - 1)) {      // last block finalizes
      const float v = atomicAdd(lacc, 0.0f);      // device-coherent read
      out[0] = v * (1.0f / (float)NROW);
    }
  }
}

extern "C" void kernel_launch(void* const* d_in, const int* in_sizes, int n_in,
                              void* d_out, int out_size, void* d_ws, size_t ws_size,
                              hipStream_t stream) {
  const float* z_i = (const float*)d_in[0];
  const float* z_j = (const float*)d_in[1];
  float* out = (float*)d_out;

  char* ws = (char*)d_ws;
  unsigned char* zn = (unsigned char*)ws;                        // 2 MB fp8
  float* pos  = (float*)(ws + 2097152);                          // 32 KB
  float* P    = (float*)(ws + 2097152 + 32768);                  // 2 MB
  float* lacc = (float*)(ws + 2097152 + 32768 + 2097152);        // 4 B
  unsigned int* counter = (unsigned int*)(ws + 2097152 + 32768 + 2097152 + 4);

  normalize_kernel<<<512, 256, 0, stream>>>(z_i, z_j, zn, lacc, counter);
  gram_kernel<<<NTILES, 256, 0, stream>>>(zn, P, pos);
  rowreduce_kernel<<<NROW / 256, 256, 0, stream>>>(P, pos, lacc, counter, out);
}